// Round 6
// baseline (279.281 us; speedup 1.0000x reference)
//
#include <hip/hip_runtime.h>
#include <hip/hip_bf16.h>

// Problem: out[b,j,k] = squash_j( s[b,j,k] ), s = sum_{i<2048,u<16} W[i,j,k,u] x[b,u,i]
// GEMM view: C[m=b(32), n=(j,k)(1024)] = A[m,(i,u)] B[(i,u),n], K=32768.
// W[i][j][k][u] strides (floats): i:16384, j:1024, k:16, u:1
// x[b][u][i]    strides (floats): b:32768, u:2048, i:1
//
// DIAGNOSTIC ROUND: K-loop runs NPASS=4 passes over the same W (result
// averaged). Purpose: push caps_mfma above the 77us harness fill so its
// counters appear in top-5, and test the dense-load theory (LDS-staged W
// with lane-dense global loads vs the previous 2-lanes-per-line pattern).

#define B_SZ   32
#define IC     2048
#define NJ     16
#define NK     64
#define SOUT   (B_SZ*NJ*NK)      // 32768
#define KSTEPS 1024              // mfma K-steps; each covers 2 i x 16 u
#define KSPLIT 64                // K-splits across grid.y
#define SPW    (KSTEPS/KSPLIT)   // 16 steps per block
#define NPASS  4                 // diagnostic W re-reads

typedef float v4f __attribute__((ext_vector_type(4)));
typedef short v8s __attribute__((ext_vector_type(8)));
typedef unsigned int v4u __attribute__((ext_vector_type(4)));

// f32 -> bf16 round-to-nearest-even (used once in xprep)
static __device__ inline ushort f2bf(float f) {
    uint32_t u = __float_as_uint(f);
    u += 0x7FFFu + ((u >> 16) & 1u);
    return (ushort)(u >> 16);
}

// hot-loop pack: two f32 -> packed bf16 pair (round-half-up + v_perm_b32)
static __device__ inline uint packbf(float f0, float f1) {
    uint u0 = __float_as_uint(f0) + 0x8000u;
    uint u1 = __float_as_uint(f1) + 0x8000u;
    return __builtin_amdgcn_perm(u1, u0, 0x07060302u);  // [bf(f1)|bf(f0)]
}

// ---------------------------------------------------------------------------
// xprep: build A-fragments in bf16.
// kk = q*8 + jj -> i_off = kk>>4, u = kk&15 within a step (2 i's x 16 u).
// A-layout (16x16x32): lane holds A[m = lane&15][kk = (lane>>4)*8 + jj].
// xb flat: [step(1024)][mt(2)][lane(64)][jj(8)] bf16.
// ---------------------------------------------------------------------------
__global__ __launch_bounds__(256)
void caps_xprep(const float* __restrict__ x, ushort* __restrict__ xb) {
    int gid  = blockIdx.x * 256 + threadIdx.x;   // 131072 threads
    int lane = gid & 63;
    int mt   = (gid >> 6) & 1;
    int step = gid >> 7;
    int q    = lane >> 4;
    int b    = mt * 16 + (lane & 15);
    int i    = 2 * step + (q >> 1);
    int u0   = (q & 1) * 8;

    const float* xp = x + (size_t)b * (16 * IC) + (size_t)u0 * IC + i;
    ushort tmp[8];
    #pragma unroll
    for (int jj = 0; jj < 8; ++jj)
        tmp[jj] = f2bf(xp[(size_t)jj * IC]);
    *(v8s*)(xb + (size_t)gid * 8) = *(const v8s*)tmp;
}

// ---------------------------------------------------------------------------
// main: block = (j, split), 256 thr = 4 waves; wave wv = k'-tile (16 k's).
// W staged to LDS with DENSE cooperative loads: thread t reads float4 at
// flat offset 4t of each 4KB j-row (lane stride 16B -> 4 lanes per 64B line,
// 16 requests/KB) -- vs the old per-fragment pattern (2 lanes/line, 64
// req/KB). Double-buffered, 1 barrier/step. Fragments via ds_read_b128.
// ---------------------------------------------------------------------------
__global__ __launch_bounds__(256)
void caps_mfma(const ushort* __restrict__ xb, const float* __restrict__ W,
               float* __restrict__ part) {
    __shared__ float buf[2][2048];    // [dbuf][ip*1024 + k*16 + u]  (8KB each)

    const int tid   = threadIdx.x;
    const int wv    = tid >> 6;       // k'-tile 0..3
    const int lane  = tid & 63;
    const int j     = blockIdx.x;     // 0..15
    const int split = blockIdx.y;     // 0..KSPLIT-1
    const int n     = lane & 15;
    const int q     = lane >> 4;
    const int i0    = split * (2 * SPW);          // 32 i's per split

    const float*  wjb   = W  + (size_t)j * 1024;  // j-row base
    const ushort* xbase = xb + (size_t)split * SPW * 1024 + (size_t)lane * 8;

    v4f acc0 = {0.f, 0.f, 0.f, 0.f};
    v4f acc1 = {0.f, 0.f, 0.f, 0.f};

    // prologue: stage step 0 into buf[0]
    {
        float4 a = *(const float4*)(wjb + (size_t)(i0 + 0) * 16384 + tid * 4);
        float4 b = *(const float4*)(wjb + (size_t)(i0 + 1) * 16384 + tid * 4);
        *(float4*)&buf[0][tid * 4]        = a;
        *(float4*)&buf[0][1024 + tid * 4] = b;
    }

    // fragment LDS base for this thread: [i-parity q>>1][k = wv*16+n][u0=(q&1)*8]
    const int fidx = (q >> 1) * 1024 + (wv * 16 + n) * 16 + (q & 1) * 8;

    #pragma unroll 1
    for (int it = 0; it < NPASS * SPW; ++it) {
        __syncthreads();                       // buf[it&1] ready; prior readers done
        const int cur = it & 1;
        const int s   = it & (SPW - 1);
        const bool have = (it + 1 < NPASS * SPW);
        const int sn  = (it + 1) & (SPW - 1);

        // issue next step's dense global loads (overlap with compute below)
        float4 ga, gb;
        if (have) {
            ga = *(const float4*)(wjb + (size_t)(i0 + 2 * sn)     * 16384 + tid * 4);
            gb = *(const float4*)(wjb + (size_t)(i0 + 2 * sn + 1) * 16384 + tid * 4);
        }

        // compute step s from buf[cur]
        const float* bp = &buf[cur][fidx];
        float4 w0 = *(const float4*)(bp);
        float4 w1 = *(const float4*)(bp + 4);
        v8s a0 = *(const v8s*)(xbase + (size_t)s * 1024);
        v8s a1 = *(const v8s*)(xbase + (size_t)s * 1024 + 512);
        v4u pk;
        pk.x = packbf(w0.x, w0.y); pk.y = packbf(w0.z, w0.w);
        pk.z = packbf(w1.x, w1.y); pk.w = packbf(w1.z, w1.w);
        v8s bb = *(v8s*)&pk;
        acc0 = __builtin_amdgcn_mfma_f32_16x16x32_bf16(a0, bb, acc0, 0, 0, 0);
        acc1 = __builtin_amdgcn_mfma_f32_16x16x32_bf16(a1, bb, acc1, 0, 0, 0);

        // write next step into the other buffer (visible after next barrier)
        if (have) {
            const int nxt = cur ^ 1;
            *(float4*)&buf[nxt][tid * 4]        = ga;
            *(float4*)&buf[nxt][1024 + tid * 4] = gb;
        }
    }

    // C/D layout: col = lane&15 = n (k'), row = q*4 + reg = m (b).
    float* pp = part + (size_t)split * SOUT + (size_t)j * NK + wv * 16 + n;
    #pragma unroll
    for (int r = 0; r < 4; ++r) {
        int m = q * 4 + r;
        pp[(size_t)m * 1024]        = acc0[r] * (1.0f / NPASS);
        pp[(size_t)(m + 16) * 1024] = acc1[r] * (1.0f / NPASS);
    }
}

// ---------------------------------------------------------------------------
// finish: sum K-splits, then squash over j (num_units axis, per torch source).
// 128 blocks = (b:32, k-chunk:4); 256 thr = (j:16, kc:16).
// ---------------------------------------------------------------------------
__global__ __launch_bounds__(256)
void caps_finish(const float* __restrict__ part, float* __restrict__ out) {
    __shared__ float ls[256];
    const int blk = blockIdx.x;
    const int b   = blk >> 2;
    const int k0  = (blk & 3) * 16;
    const int t   = threadIdx.x;
    const int jj  = t >> 4;
    const int kc  = t & 15;
    const size_t idx = (size_t)b * 1024 + (size_t)jj * NK + k0 + kc;

    float s = 0.0f;
    #pragma unroll 8
    for (int sp = 0; sp < KSPLIT; ++sp)
        s += part[(size_t)sp * SOUT + idx];
    ls[t] = s;
    __syncthreads();

    float msq = 0.0f;
    #pragma unroll
    for (int j2 = 0; j2 < NJ; ++j2) {
        float v = ls[j2 * 16 + kc];
        msq += v * v;
    }
    float mag = sqrtf(msq);
    out[idx] = s * (mag / (1.0f + msq));
}

extern "C" void kernel_launch(void* const* d_in, const int* in_sizes, int n_in,
                              void* d_out, int out_size, void* d_ws, size_t ws_size,
                              hipStream_t stream) {
    const float* x = (const float*)d_in[0];   // (32, 16, 2048) f32
    const float* W = (const float*)d_in[1];   // (1, 2048, 16, 64, 16) f32
    float* out  = (float*)d_out;              // (32, 16, 64) f32

    float*  part = (float*)d_ws;                            // 8 MB
    ushort* xb   = (ushort*)(part + (size_t)KSPLIT * SOUT); // + 2 MB

    caps_xprep <<<512,               256, 0, stream>>>(x, xb);
    caps_mfma  <<<dim3(16, KSPLIT),  256, 0, stream>>>(xb, W, part);
    caps_finish<<<128,               256, 0, stream>>>(part, out);
}

// Round 7
// 208.024 us; speedup vs baseline: 1.3425x; 1.3425x over previous
//
#include <hip/hip_runtime.h>
#include <hip/hip_bf16.h>

// Problem: out[b,j,k] = squash_j( s[b,j,k] ), s = sum_{i<2048,u<16} W[i,j,k,u] x[b,u,i]
// GEMM view: C[m=b(32), n=(j,k)(1024)] = A[m,(i,u)] B[(i,u),n], K=32768.
// W[i][j][k][u] strides (floats): i:16384, j:1024, k:16, u:1
// x[b][u][i]    strides (floats): b:32768, u:2048, i:1
//
// R6 diagnostic: dense cooperative W staging = 3.8 TB/s delivered vs 2.4 TB/s
// for per-fragment (64B-strided) loads; limiter was 1-barrier-per-8KB
// serialization (4000 cyc/iter), not DRAM (FETCH showed L3 absorbing).
// R7: same dense pattern, 32 KB per barrier, async global_load_lds dbuf.

#define B_SZ   32
#define IC     2048
#define NJ     16
#define NK     64
#define SOUT   (B_SZ*NJ*NK)      // 32768
#define KSTEPS 1024              // mfma K-steps; each covers 2 i x 16 u
#define KSPLIT 32                // grid.y: 16*32=512 blocks = 2/CU, one round
#define SPW    (KSTEPS/KSPLIT)   // 32 steps per block
#define SEGST  4                 // steps per segment
#define NSEG   (SPW/SEGST)       // 8 segments
#define RPS    (2*SEGST)         // 8 i-rows per segment = 32 KB

typedef float v4f __attribute__((ext_vector_type(4)));
typedef short v8s __attribute__((ext_vector_type(8)));
typedef unsigned int v4u __attribute__((ext_vector_type(4)));

// f32 -> bf16 round-to-nearest-even (used once in xprep)
static __device__ inline ushort f2bf(float f) {
    uint32_t u = __float_as_uint(f);
    u += 0x7FFFu + ((u >> 16) & 1u);
    return (ushort)(u >> 16);
}

// hot-loop pack: two f32 -> packed bf16 pair (round-half-up + v_perm_b32)
static __device__ inline uint packbf(float f0, float f1) {
    uint u0 = __float_as_uint(f0) + 0x8000u;
    uint u1 = __float_as_uint(f1) + 0x8000u;
    return __builtin_amdgcn_perm(u1, u0, 0x07060302u);  // [bf(f1)|bf(f0)]
}

// ---------------------------------------------------------------------------
// xprep: build A-fragments in bf16.
// kk = q*8 + jj -> i_off = kk>>4, u = kk&15 within a step (2 i's x 16 u).
// A-layout (16x16x32): lane holds A[m = lane&15][kk = (lane>>4)*8 + jj].
// xb flat: [step(1024)][mt(2)][lane(64)][jj(8)] bf16.
// ---------------------------------------------------------------------------
__global__ __launch_bounds__(256)
void caps_xprep(const float* __restrict__ x, ushort* __restrict__ xb) {
    int gid  = blockIdx.x * 256 + threadIdx.x;   // 131072 threads
    int lane = gid & 63;
    int mt   = (gid >> 6) & 1;
    int step = gid >> 7;
    int q    = lane >> 4;
    int b    = mt * 16 + (lane & 15);
    int i    = 2 * step + (q >> 1);
    int u0   = (q & 1) * 8;

    const float* xp = x + (size_t)b * (16 * IC) + (size_t)u0 * IC + i;
    ushort tmp[8];
    #pragma unroll
    for (int jj = 0; jj < 8; ++jj)
        tmp[jj] = f2bf(xp[(size_t)jj * IC]);
    *(v8s*)(xb + (size_t)gid * 8) = *(const v8s*)tmp;
}

// ---------------------------------------------------------------------------
// main: block = (j, split), 256 thr = 4 waves; wave wv = k'-tile (16 k's).
// Dense async staging: global_load_lds width 16, thread t handles bytes
// [16t,16t+16) of each 4 KB i-row (4 lanes/64B line). Segment = 8 rows =
// 32 KB per barrier; double-buffered (64 KB LDS -> 2 blocks/CU). Prefetch
// of segment sg+1 issues right after barrier(sg); the compiler's
// vmcnt(0)-before-barrier drain lands a full iteration later.
// ---------------------------------------------------------------------------
__global__ __launch_bounds__(256)
void caps_mfma(const ushort* __restrict__ xb, const float* __restrict__ W,
               float* __restrict__ part) {
    __shared__ float buf[2][RPS * 1024];   // 2 x 32 KB

    const int tid   = threadIdx.x;
    const int wv    = tid >> 6;       // k'-tile 0..3
    const int lane  = tid & 63;
    const int j     = blockIdx.x;     // 0..15
    const int split = blockIdx.y;     // 0..KSPLIT-1
    const int n     = lane & 15;
    const int q     = lane >> 4;
    const int i0    = split * (2 * SPW);          // 64 i's per split

    const float*  wjb   = W  + (size_t)j * 1024;  // j-row base
    const ushort* xbase = xb + (size_t)split * SPW * 1024 + (size_t)lane * 8;

    v4f acc0 = {0.f, 0.f, 0.f, 0.f};
    v4f acc1 = {0.f, 0.f, 0.f, 0.f};

    // stage segment seg into buf[bufsel]: 8 rows x 4 KB, lds dest is
    // wave-uniform base + lane*16 (matches tid*16 global pattern)
    #define STAGE_SEG(seg, bufsel)                                            \
        do {                                                                  \
            _Pragma("unroll")                                                 \
            for (int r = 0; r < RPS; ++r) {                                   \
                const float* g = wjb +                                        \
                    (size_t)(i0 + (seg) * RPS + r) * 16384 + tid * 4;         \
                __builtin_amdgcn_global_load_lds(                             \
                    (const __attribute__((address_space(1))) void*)g,         \
                    (__attribute__((address_space(3))) void*)                 \
                        &buf[bufsel][r * 1024 + wv * 256],                    \
                    16, 0, 0);                                                \
            }                                                                 \
        } while (0)

    STAGE_SEG(0, 0);

    // fragment offset within an i-pair (2 rows = 2048 floats):
    // row parity (q>>1), k = wv*16+n, u0 = (q&1)*8
    const int fo = (wv * 16 + n) * 16 + (q & 1) * 8;

    #pragma unroll 1
    for (int sg = 0; sg < NSEG; ++sg) {
        const int cur = sg & 1;
        __syncthreads();   // drains buf[cur] loads; all waves done with buf[cur^1]
        if (sg + 1 < NSEG) STAGE_SEG(sg + 1, cur ^ 1);

        // prefetch this segment's xb fragments into registers (8 x 16 B)
        v8s xa0[SEGST], xa1[SEGST];
        #pragma unroll
        for (int t = 0; t < SEGST; ++t) {
            const ushort* xp = xbase + (size_t)(sg * SEGST + t) * 1024;
            xa0[t] = *(const v8s*)(xp);
            xa1[t] = *(const v8s*)(xp + 512);
        }

        #pragma unroll
        for (int t = 0; t < SEGST; ++t) {
            const float* bp = &buf[cur][(2 * t + (q >> 1)) * 1024 + fo];
            float4 w0 = *(const float4*)(bp);
            float4 w1 = *(const float4*)(bp + 4);
            v4u pk;
            pk.x = packbf(w0.x, w0.y); pk.y = packbf(w0.z, w0.w);
            pk.z = packbf(w1.x, w1.y); pk.w = packbf(w1.z, w1.w);
            v8s bb = *(v8s*)&pk;
            acc0 = __builtin_amdgcn_mfma_f32_16x16x32_bf16(xa0[t], bb, acc0, 0, 0, 0);
            acc1 = __builtin_amdgcn_mfma_f32_16x16x32_bf16(xa1[t], bb, acc1, 0, 0, 0);
        }
    }

    // C/D layout: col = lane&15 = n (k'), row = q*4 + reg = m (b).
    float* pp = part + (size_t)split * SOUT + (size_t)j * NK + wv * 16 + n;
    #pragma unroll
    for (int r = 0; r < 4; ++r) {
        int m = q * 4 + r;
        pp[(size_t)m * 1024]        = acc0[r];
        pp[(size_t)(m + 16) * 1024] = acc1[r];
    }
}

// ---------------------------------------------------------------------------
// finish: sum K-splits, then squash over j (num_units axis, per torch source).
// 128 blocks = (b:32, k-chunk:4); 256 thr = (j:16, kc:16).
// ---------------------------------------------------------------------------
__global__ __launch_bounds__(256)
void caps_finish(const float* __restrict__ part, float* __restrict__ out) {
    __shared__ float ls[256];
    const int blk = blockIdx.x;
    const int b   = blk >> 2;
    const int k0  = (blk & 3) * 16;
    const int t   = threadIdx.x;
    const int jj  = t >> 4;
    const int kc  = t & 15;
    const size_t idx = (size_t)b * 1024 + (size_t)jj * NK + k0 + kc;

    float s = 0.0f;
    #pragma unroll 8
    for (int sp = 0; sp < KSPLIT; ++sp)
        s += part[(size_t)sp * SOUT + idx];
    ls[t] = s;
    __syncthreads();

    float msq = 0.0f;
    #pragma unroll
    for (int j2 = 0; j2 < NJ; ++j2) {
        float v = ls[j2 * 16 + kc];
        msq += v * v;
    }
    float mag = sqrtf(msq);
    out[idx] = s * (mag / (1.0f + msq));
}

extern "C" void kernel_launch(void* const* d_in, const int* in_sizes, int n_in,
                              void* d_out, int out_size, void* d_ws, size_t ws_size,
                              hipStream_t stream) {
    const float* x = (const float*)d_in[0];   // (32, 16, 2048) f32
    const float* W = (const float*)d_in[1];   // (1, 2048, 16, 64, 16) f32
    float* out  = (float*)d_out;              // (32, 16, 64) f32

    float*  part = (float*)d_ws;                            // 4 MB
    ushort* xb   = (ushort*)(part + (size_t)KSPLIT * SOUT); // + 2 MB

    caps_xprep <<<512,               256, 0, stream>>>(x, xb);
    caps_mfma  <<<dim3(16, KSPLIT),  256, 0, stream>>>(xb, W, part);
    caps_finish<<<128,               256, 0, stream>>>(part, out);
}